// Round 4
// baseline (674.789 us; speedup 1.0000x reference)
//
#include <hip/hip_runtime.h>
#include <math.h>

#define B 4096
#define D 512
#define KC 4096
#define NIDX 131072
#define RR 3
#define TEMP 0.07f
#define M_II 14.5f   // |sim|/0.07 <= ~14.43 incl bf16 slop
#define M_IP 4.0f    // |sim|/density <= ~3.37 incl slop

typedef __bf16 bf16x8 __attribute__((ext_vector_type(8)));
typedef float f32x4 __attribute__((ext_vector_type(4)));

__device__ __forceinline__ void gload_lds16(const void* g, void* l) {
  __builtin_amdgcn_global_load_lds(
      (const __attribute__((address_space(1))) unsigned int*)g,
      (__attribute__((address_space(3))) unsigned int*)l, 16, 0, 0);
}

__device__ __forceinline__ float dot8(float4 a0, float4 a1, float4 b0, float4 b1) {
  return a0.x * b0.x + a0.y * b0.y + a0.z * b0.z + a0.w * b0.w
       + a1.x * b1.x + a1.y * b1.y + a1.z * b1.z + a1.w * b1.w;
}

// ---------------- K1: fused prep: norm->bf16, proto gather->bf16, rho ----------------
// 9216 blocks x 256 threads; each wave handles one task u in [0, 9B).
__global__ __launch_bounds__(256) void prep_kernel(
    const float* __restrict__ audio, const float* __restrict__ frame,
    const float* __restrict__ a_cent, const float* __restrict__ a_dens,
    const float* __restrict__ f_cent, const float* __restrict__ f_dens,
    const int* __restrict__ vidx, const int* __restrict__ a_i2c,
    const int* __restrict__ f_i2c,
    __bf16* __restrict__ Xa, __bf16* __restrict__ Xf,
    __bf16* __restrict__ Yf, __bf16* __restrict__ Ya,
    float* __restrict__ invdd_f, float* __restrict__ invdd_a,
    float* __restrict__ rho) {
  const int u = blockIdx.x * 4 + (threadIdx.x >> 6);
  const int lane = threadIdx.x & 63;

  if (u < 8 * B) {
    const float* src; __bf16* dst;
    float* invArr = nullptr; const float* densp = nullptr;
    int slot = 0; size_t densIdx = 0;
    if (u < 2 * B) {
      if (u < B) { src = audio + (size_t)u * D; dst = Xa + (size_t)u * D; }
      else       { src = frame + (size_t)(u - B) * D; dst = Xf + (size_t)(u - B) * D; }
    } else {
      int q = u - 2 * B;
      int side = q / (RR * B);
      int rem = q - side * (RR * B);
      int r = rem / B;
      int j = rem - r * B;
      int idx = vidx[j];
      int pid;
      if (side == 0) {
        pid = f_i2c[r * NIDX + idx];
        src = f_cent + ((size_t)r * KC + pid) * D;
        dst = Yf + ((size_t)r * B + j) * D;
        invArr = invdd_f; densp = f_dens;
      } else {
        pid = a_i2c[r * NIDX + idx];
        src = a_cent + ((size_t)r * KC + pid) * D;
        dst = Ya + ((size_t)r * B + j) * D;
        invArr = invdd_a; densp = a_dens;
      }
      slot = r * B + j;
      densIdx = (size_t)r * KC + pid;
    }
    const float4* s4 = (const float4*)src + lane * 2;
    float4 v0 = s4[0], v1 = s4[1];
    float ss = dot8(v0, v1, v0, v1);
    #pragma unroll
    for (int off = 32; off >= 1; off >>= 1) ss += __shfl_xor(ss, off, 64);
    float invn = 1.f / fmaxf(sqrtf(ss), 1e-12f);
    __bf16 o[8];
    o[0] = (__bf16)(v0.x * invn); o[1] = (__bf16)(v0.y * invn);
    o[2] = (__bf16)(v0.z * invn); o[3] = (__bf16)(v0.w * invn);
    o[4] = (__bf16)(v1.x * invn); o[5] = (__bf16)(v1.y * invn);
    o[6] = (__bf16)(v1.z * invn); o[7] = (__bf16)(v1.w * invn);
    *(bf16x8*)(dst + lane * 8) = *(bf16x8*)o;
    if (invArr && lane == 0) invArr[slot] = 1.f / densp[densIdx];
  } else {
    const int i = u - 8 * B;
    const int idx = vidx[i];
    const float4* x4 = (const float4*)(audio + (size_t)i * D) + lane * 2;
    const float4* y4 = (const float4*)(frame + (size_t)i * D) + lane * 2;
    float4 a0 = x4[0], a1 = x4[1], f0 = y4[0], f1 = y4[1];
    float saf = dot8(a0, a1, f0, f1);
    float sa = dot8(a0, a1, a0, a1);
    float sf = dot8(f0, f1, f0, f1);
    float pc = 0.f;
    for (int r = 0; r < RR; ++r) {
      int ap = a_i2c[r * NIDX + idx];
      int fp = f_i2c[r * NIDX + idx];
      const float4* c4 = (const float4*)(a_cent + ((size_t)r * KC + ap) * D) + lane * 2;
      const float4* d4 = (const float4*)(f_cent + ((size_t)r * KC + fp) * D) + lane * 2;
      float4 c0 = c4[0], c1 = c4[1], e0 = d4[0], e1 = d4[1];
      pc += dot8(c0, c1, e0, e1);
    }
    #pragma unroll
    for (int off = 32; off >= 1; off >>= 1) {
      saf += __shfl_xor(saf, off, 64);
      sa  += __shfl_xor(sa, off, 64);
      sf  += __shfl_xor(sf, off, 64);
      pc  += __shfl_xor(pc, off, 64);
    }
    if (lane == 0)
      rho[i] = saf / (fmaxf(sqrtf(sa), 1e-12f) * fmaxf(sqrtf(sf), 1e-12f)) - pc;
  }
}

// ---------------- K2: fused bf16-MFMA GEMM + fixed-max LSE partials ----------------
// grid (32, 7, 4): x=row-block (128 rows), y=job-slot, z=column quarter (1024 cols)
// job-slot 0 = ii (computes BOTH row-LSE partials for v2f and col-LSE partials
// for f2v: the f2v ii matrix is the transpose of the v2f one, same diagonal).
// job-slots 1..6 map to original jobs 2..7 (inst-proto).
__global__ __launch_bounds__(256, 4) void lse_mfma_kernel(
    const __bf16* __restrict__ Xa, const __bf16* __restrict__ Xf,
    const __bf16* __restrict__ Yf, const __bf16* __restrict__ Ya,
    const float* __restrict__ invdd_f, const float* __restrict__ invdd_a,
    float* __restrict__ sp, float* __restrict__ colsp,
    float* __restrict__ diagAll) {
  __shared__ __bf16 As[128 * 32];      // [row][64B] lane-linear (glds constraint)
  __shared__ __bf16 Bs[128 * 32];
  __shared__ float inv_lds[2][132];    // double-buffered: no cross-wave race
  __shared__ float part_s[2 * 128];
  __shared__ float colpart[2][128];

  const int yy = blockIdx.y;
  const int job = (yy == 0) ? 0 : yy + 1;
  const int hf = blockIdx.z;
  const int i0 = blockIdx.x * 128;

  const __bf16* Ab; const __bf16* Bb; const float* invArr = nullptr;
  if (job == 0)      { Ab = Xa; Bb = Xf; }
  else if (job <= 4) { Ab = Xa; Bb = Yf + (size_t)(job - 2) * B * D;
                       invArr = invdd_f + (job - 2) * B; }
  else               { Ab = Xf; Bb = Ya + (size_t)(job - 5) * B * D;
                       invArr = invdd_a + (job - 5) * B; }
  const bool ii = (job == 0);
  const float invT = 1.f / TEMP;
  const float inv0 = ii ? invT : invArr[0];
  const float MJ = ii ? M_II : M_IP;

  const int tid = threadIdx.x;
  const int wv = tid >> 6;
  const int lane = tid & 63;
  const int wr = (wv >> 1) * 64;
  const int wc = (wv & 1) * 64;
  const int g = lane >> 4;
  const int cl = lane & 15;

  // staging: XOR-swizzled global source so LDS fragment reads are 2-way (free)
  const int srow = lane >> 2;
  const int skoff = (((lane & 3) ^ ((lane >> 3) & 3)) * 16);
  const int c0row = wv * 16 + srow;
  const int c1row = 64 + wv * 16 + srow;
  const char* gA0 = (const char*)Ab + (size_t)(i0 + c0row) * (D * 2) + skoff;
  const char* gA1 = (const char*)Ab + (size_t)(i0 + c1row) * (D * 2) + skoff;
  __bf16* lA0 = As + wv * 512;
  __bf16* lA1 = As + 2048 + wv * 512;
  __bf16* lB0 = Bs + wv * 512;
  __bf16* lB1 = Bs + 2048 + wv * 512;

  const int csw = (g ^ ((cl >> 1) & 3)) * 8;   // swizzled k-chunk for frag reads
  int aoff[4], boff[4];
  #pragma unroll
  for (int t = 0; t < 4; ++t) {
    aoff[t] = (wr + t * 16 + cl) * 32 + csw;
    boff[t] = (wc + t * 16 + cl) * 32 + csw;
  }

  float sacc[4][4];
  #pragma unroll
  for (int ri = 0; ri < 4; ++ri)
    #pragma unroll
    for (int v = 0; v < 4; ++v) sacc[ri][v] = 0.f;

  for (int jt = hf * 8; jt < hf * 8 + 8; ++jt) {
    const int j0 = jt * 128;
    float* invL = inv_lds[jt & 1];
    if (!ii && tid < 130) {
      int idx = j0 + tid; if (idx > B - 1) idx = B - 1;
      invL[tid] = invArr[idx];
    }
    const char* gB0 = (const char*)Bb + (size_t)(j0 + c0row) * (D * 2) + skoff;
    const char* gB1 = (const char*)Bb + (size_t)(j0 + c1row) * (D * 2) + skoff;

    f32x4 acc[4][4];
    #pragma unroll
    for (int ri = 0; ri < 4; ++ri)
      #pragma unroll
      for (int ci = 0; ci < 4; ++ci) acc[ri][ci] = (f32x4){0.f, 0.f, 0.f, 0.f};

    for (int kt = 0; kt < 16; ++kt) {
      __syncthreads();
      const int kb = kt * 64;
      gload_lds16(gA0 + kb, lA0);
      gload_lds16(gA1 + kb, lA1);
      gload_lds16(gB0 + kb, lB0);
      gload_lds16(gB1 + kb, lB1);
      __syncthreads();
      bf16x8 af[4], bfr[4];
      #pragma unroll
      for (int t = 0; t < 4; ++t) {
        af[t] = *(const bf16x8*)(As + aoff[t]);
        bfr[t] = *(const bf16x8*)(Bs + boff[t]);
      }
      #pragma unroll
      for (int ri = 0; ri < 4; ++ri)
        #pragma unroll
        for (int ci = 0; ci < 4; ++ci)
          acc[ri][ci] = __builtin_amdgcn_mfma_f32_16x16x32_bf16(
              af[ri], bfr[ci], acc[ri][ci], 0, 0, 0);
    }

    // epilogue: fixed-max accumulation (rows), plus column partials for job0
    float csum[4] = {0.f, 0.f, 0.f, 0.f};
    #pragma unroll
    for (int ri = 0; ri < 4; ++ri) {
      #pragma unroll
      for (int v = 0; v < 4; ++v) {
        const int gi = i0 + wr + ri * 16 + g * 4 + v;
        float acc4 = 0.f;
        #pragma unroll
        for (int ci = 0; ci < 4; ++ci) {
          const int jloc = wc + ci * 16 + cl;
          const int gj = j0 + jloc;
          float sc;
          if (ii) sc = invT;
          else    sc = (gj == gi) ? inv0 : invL[(gj < gi) ? (jloc + 1) : jloc];
          float lv = acc[ri][ci][v] * sc;
          if (gj == gi) diagAll[(size_t)job * B + gi] = lv;
          float ev = __expf(lv - MJ);
          acc4 += ev;
          if (ii) csum[ci] += ev;
        }
        sacc[ri][v] += acc4;
      }
    }
    if (ii) {
      // column partials: reduce over the wave's 64 rows, combine row-half waves
      #pragma unroll
      for (int ci = 0; ci < 4; ++ci) {
        csum[ci] += __shfl_xor(csum[ci], 16, 64);
        csum[ci] += __shfl_xor(csum[ci], 32, 64);
      }
      if (g == 0) {
        #pragma unroll
        for (int ci = 0; ci < 4; ++ci)
          colpart[wv >> 1][wc + ci * 16 + cl] = csum[ci];
      }
      __syncthreads();
      if (tid < 128)
        colsp[(size_t)blockIdx.x * B + j0 + tid] =
            colpart[0][tid] + colpart[1][tid];
    }
  }

  // single end-of-kernel reduction: 16 lanes (columns) -> LDS -> cross-wave pair
  #pragma unroll
  for (int ri = 0; ri < 4; ++ri) {
    #pragma unroll
    for (int v = 0; v < 4; ++v) {
      float s = sacc[ri][v];
      #pragma unroll
      for (int off = 8; off >= 1; off >>= 1) s += __shfl_xor(s, off, 64);
      if (cl == 0) part_s[(wv & 1) * 128 + wr + ri * 16 + g * 4 + v] = s;
    }
  }
  __syncthreads();
  if (tid < 128) {
    size_t o = ((size_t)job * 4 + hf) * B + i0 + tid;
    sp[o] = part_s[tid] + part_s[128 + tid];
  }
}

// ---------------- K3: fused LSE-merge (blocks 0..127) + stable rank (128..143) ----------------
__global__ __launch_bounds__(256) void merge_rank_kernel(
    const float* __restrict__ sp, const float* __restrict__ colsp,
    const float* __restrict__ diagAll, const float* __restrict__ rho,
    float* __restrict__ lossAll, int* __restrict__ rankArr,
    float* __restrict__ srho) {
  __shared__ float lr[B];
  const int blk = blockIdx.x;
  const int t = threadIdx.x;
  if (blk < 128) {
    int idx = blk * 256 + t;          // 0 .. 8*B-1
    int job = idx >> 12;
    int i = idx & (B - 1);
    if (job == 1) {
      // f2v inst-inst: column-LSE of job0's matrix; diag equals job0's diag
      float stot = 0.f;
      #pragma unroll 4
      for (int x = 0; x < 32; ++x) stot += colsp[(size_t)x * B + i];
      lossAll[idx] = M_II + logf(stot) - diagAll[i];
    } else {
      const float* s4 = sp + (size_t)job * 4 * B + i;
      float stot = s4[0] + s4[(size_t)B] + s4[(size_t)2 * B] + s4[(size_t)3 * B];
      float MJ = (job < 2) ? M_II : M_IP;
      lossAll[idx] = MJ + logf(stot) - diagAll[(size_t)job * B + i];
    }
  } else {
    int i = (blk - 128) * 256 + t;
    for (int k = t; k < B; k += 256) lr[k] = rho[k];
    __syncthreads();
    float my = lr[i];
    int rk = 0;
    for (int j = 0; j < B; ++j) {
      float v = lr[j];
      rk += (v < my) || (v == my && j < i);   // stable: ties by index
    }
    rankArr[i] = rk;
    srho[rk] = my;
  }
}

// ---------------- K4: stats + gaussian pdf + cumsum + weights + final (one block) ----------------
__global__ __launch_bounds__(256) void cdf_final_kernel(
    const float* __restrict__ srho, const int* __restrict__ rankArr,
    const float* __restrict__ lossAll, float* __restrict__ out) {
  __shared__ float pdf[B];             // becomes yarr in place
  __shared__ float red[256];
  __shared__ float r1[256], r2[256];
  __shared__ float mv[2];
  const int t = threadIdx.x;
  float s = 0.f;
  for (int i = t; i < B; i += 256) s += srho[i];
  red[t] = s; __syncthreads();
  for (int off = 128; off >= 1; off >>= 1) {
    if (t < off) red[t] += red[t + off];
    __syncthreads();
  }
  float mean = red[0] / (float)B;
  __syncthreads();
  float v = 0.f;
  for (int i = t; i < B; i += 256) { float d = srho[i] - mean; v += d * d; }
  red[t] = v; __syncthreads();
  for (int off = 128; off >= 1; off >>= 1) {
    if (t < off) red[t] += red[t + off];
    __syncthreads();
  }
  if (t == 0) {
    float sd = sqrtf(red[0] / (float)B);
    mv[0] = mean + 0.3f * sd;          // mu = mean + DELTA*std
    mv[1] = sd * sqrtf(2.0f);          // sigma = std*sqrt(KA)
  }
  __syncthreads();
  float mu = mv[0], sg = mv[1];
  float c = 1.f / (2.5066282746310002f * sg);
  for (int k = t; k < B; k += 256) {
    float z = (srho[k] - mu) / sg;
    pdf[k] = expf(-0.5f * z * z) * c;
  }
  __syncthreads();
  const int base = t * (B / 256);
  float ps = 0.f;
  for (int e = 0; e < B / 256; ++e) ps += pdf[base + e];
  red[t] = ps; __syncthreads();
  if (t == 0) {
    float run = 0.f;
    for (int q = 0; q < 256; ++q) { float tmp = red[q]; red[q] = run; run += tmp; }
  }
  __syncthreads();
  float run = red[t];
  for (int e = 0; e < B / 256; ++e) { run += pdf[base + e]; pdf[base + e] = run; }
  __syncthreads();
  // ---- final: weights from rank, weighted means, scalar out ----
  const float ylast = pdf[B - 1];
  float sw = 0.f, s1 = 0.f, s2 = 0.f;
  for (int i = t; i < B; i += 256) {
    float wi = pdf[rankArr[i]] / ylast;
    float lpv = lossAll[2 * B + i] * (1.f / 27.f) + lossAll[3 * B + i] * (1.f / 9.f)
              + lossAll[4 * B + i] * (1.f / 3.f);
    float lpf = lossAll[5 * B + i] * (1.f / 27.f) + lossAll[6 * B + i] * (1.f / 9.f)
              + lossAll[7 * B + i] * (1.f / 3.f);
    sw += wi;
    s1 += wi * (lossAll[i] + lpv);
    s2 += wi * (lossAll[B + i] + lpf);
  }
  red[t] = sw; r1[t] = s1; r2[t] = s2; __syncthreads();
  for (int off = 128; off >= 1; off >>= 1) {
    if (t < off) { red[t] += red[t + off]; r1[t] += r1[t + off]; r2[t] += r2[t + off]; }
    __syncthreads();
  }
  if (t == 0) out[0] = r1[0] / red[0] + r2[0] / red[0];
}

extern "C" void kernel_launch(void* const* d_in, const int* in_sizes, int n_in,
                              void* d_out, int out_size, void* d_ws, size_t ws_size,
                              hipStream_t stream) {
  const float* audio  = (const float*)d_in[0];
  const float* frame  = (const float*)d_in[1];
  const float* a_cent = (const float*)d_in[2];
  const float* a_dens = (const float*)d_in[3];
  const float* f_cent = (const float*)d_in[4];
  const float* f_dens = (const float*)d_in[5];
  const int* vidx  = (const int*)d_in[6];
  const int* a_i2c = (const int*)d_in[7];
  const int* f_i2c = (const int*)d_in[8];
  float* out = (float*)d_out;

  const size_t BD = (size_t)B * D;
  char* base = (char*)d_ws;
  __bf16* Xa = (__bf16*)base;              base += BD * 2;
  __bf16* Xf = (__bf16*)base;              base += BD * 2;
  __bf16* Yf = (__bf16*)base;              base += 3 * BD * 2;
  __bf16* Ya = (__bf16*)base;              base += 3 * BD * 2;
  float* invdd_f = (float*)base;           base += 3 * B * 4;
  float* invdd_a = (float*)base;           base += 3 * B * 4;
  float* rho     = (float*)base;           base += B * 4;
  float* sp      = (float*)base;           base += 32 * B * 4;
  float* colsp   = (float*)base;           base += 32 * B * 4;
  float* diagAll = (float*)base;           base += 8 * B * 4;
  float* lossAll = (float*)base;           base += 8 * B * 4;
  float* srho    = (float*)base;           base += B * 4;
  int*   rankArr = (int*)base;

  prep_kernel<<<(9 * B) / 4, 256, 0, stream>>>(audio, frame, a_cent, a_dens,
                                               f_cent, f_dens, vidx, a_i2c, f_i2c,
                                               Xa, Xf, Yf, Ya, invdd_f, invdd_a, rho);

  dim3 g2(B / 128, 7, 4);
  lse_mfma_kernel<<<g2, 256, 0, stream>>>(Xa, Xf, Yf, Ya, invdd_f, invdd_a,
                                          sp, colsp, diagAll);

  merge_rank_kernel<<<144, 256, 0, stream>>>(sp, colsp, diagAll, rho,
                                             lossAll, rankArr, srho);
  cdf_final_kernel<<<1, 256, 0, stream>>>(srho, rankArr, lossAll, out);
}

// Round 5
// 447.170 us; speedup vs baseline: 1.5090x; 1.5090x over previous
//
#include <hip/hip_runtime.h>
#include <math.h>

#define B 4096
#define D 512
#define KC 4096
#define NIDX 131072
#define RR 3
#define TEMP 0.07f
#define M_II 14.5f   // |sim|/0.07 <= ~14.43 incl bf16 slop
#define M_IP 4.0f    // |sim|/density <= ~3.37 incl slop

typedef __bf16 bf16x8 __attribute__((ext_vector_type(8)));
typedef float f32x4 __attribute__((ext_vector_type(4)));

__device__ __forceinline__ void gload_lds16(const void* g, void* l) {
  __builtin_amdgcn_global_load_lds(
      (const __attribute__((address_space(1))) unsigned int*)g,
      (__attribute__((address_space(3))) unsigned int*)l, 16, 0, 0);
}

__device__ __forceinline__ float dot8(float4 a0, float4 a1, float4 b0, float4 b1) {
  return a0.x * b0.x + a0.y * b0.y + a0.z * b0.z + a0.w * b0.w
       + a1.x * b1.x + a1.y * b1.y + a1.z * b1.z + a1.w * b1.w;
}

// ---------------- K1: fused prep: norm->bf16, proto gather->bf16, rho ----------------
// 9216 blocks x 256 threads; each wave handles one task u in [0, 9B).
__global__ __launch_bounds__(256) void prep_kernel(
    const float* __restrict__ audio, const float* __restrict__ frame,
    const float* __restrict__ a_cent, const float* __restrict__ a_dens,
    const float* __restrict__ f_cent, const float* __restrict__ f_dens,
    const int* __restrict__ vidx, const int* __restrict__ a_i2c,
    const int* __restrict__ f_i2c,
    __bf16* __restrict__ Xa, __bf16* __restrict__ Xf,
    __bf16* __restrict__ Yf, __bf16* __restrict__ Ya,
    float* __restrict__ invdd_f, float* __restrict__ invdd_a,
    float* __restrict__ rho) {
  const int u = blockIdx.x * 4 + (threadIdx.x >> 6);
  const int lane = threadIdx.x & 63;

  if (u < 8 * B) {
    const float* src; __bf16* dst;
    float* invArr = nullptr; const float* densp = nullptr;
    int slot = 0; size_t densIdx = 0;
    if (u < 2 * B) {
      if (u < B) { src = audio + (size_t)u * D; dst = Xa + (size_t)u * D; }
      else       { src = frame + (size_t)(u - B) * D; dst = Xf + (size_t)(u - B) * D; }
    } else {
      int q = u - 2 * B;
      int side = q / (RR * B);
      int rem = q - side * (RR * B);
      int r = rem / B;
      int j = rem - r * B;
      int idx = vidx[j];
      int pid;
      if (side == 0) {
        pid = f_i2c[r * NIDX + idx];
        src = f_cent + ((size_t)r * KC + pid) * D;
        dst = Yf + ((size_t)r * B + j) * D;
        invArr = invdd_f; densp = f_dens;
      } else {
        pid = a_i2c[r * NIDX + idx];
        src = a_cent + ((size_t)r * KC + pid) * D;
        dst = Ya + ((size_t)r * B + j) * D;
        invArr = invdd_a; densp = a_dens;
      }
      slot = r * B + j;
      densIdx = (size_t)r * KC + pid;
    }
    const float4* s4 = (const float4*)src + lane * 2;
    float4 v0 = s4[0], v1 = s4[1];
    float ss = dot8(v0, v1, v0, v1);
    #pragma unroll
    for (int off = 32; off >= 1; off >>= 1) ss += __shfl_xor(ss, off, 64);
    float invn = 1.f / fmaxf(sqrtf(ss), 1e-12f);
    __bf16 o[8];
    o[0] = (__bf16)(v0.x * invn); o[1] = (__bf16)(v0.y * invn);
    o[2] = (__bf16)(v0.z * invn); o[3] = (__bf16)(v0.w * invn);
    o[4] = (__bf16)(v1.x * invn); o[5] = (__bf16)(v1.y * invn);
    o[6] = (__bf16)(v1.z * invn); o[7] = (__bf16)(v1.w * invn);
    *(bf16x8*)(dst + lane * 8) = *(bf16x8*)o;
    if (invArr && lane == 0) invArr[slot] = 1.f / densp[densIdx];
  } else {
    const int i = u - 8 * B;
    const int idx = vidx[i];
    const float4* x4 = (const float4*)(audio + (size_t)i * D) + lane * 2;
    const float4* y4 = (const float4*)(frame + (size_t)i * D) + lane * 2;
    float4 a0 = x4[0], a1 = x4[1], f0 = y4[0], f1 = y4[1];
    float saf = dot8(a0, a1, f0, f1);
    float sa = dot8(a0, a1, a0, a1);
    float sf = dot8(f0, f1, f0, f1);
    float pc = 0.f;
    for (int r = 0; r < RR; ++r) {
      int ap = a_i2c[r * NIDX + idx];
      int fp = f_i2c[r * NIDX + idx];
      const float4* c4 = (const float4*)(a_cent + ((size_t)r * KC + ap) * D) + lane * 2;
      const float4* d4 = (const float4*)(f_cent + ((size_t)r * KC + fp) * D) + lane * 2;
      float4 c0 = c4[0], c1 = c4[1], e0 = d4[0], e1 = d4[1];
      pc += dot8(c0, c1, e0, e1);
    }
    #pragma unroll
    for (int off = 32; off >= 1; off >>= 1) {
      saf += __shfl_xor(saf, off, 64);
      sa  += __shfl_xor(sa, off, 64);
      sf  += __shfl_xor(sf, off, 64);
      pc  += __shfl_xor(pc, off, 64);
    }
    if (lane == 0)
      rho[i] = saf / (fmaxf(sqrtf(sa), 1e-12f) * fmaxf(sqrtf(sf), 1e-12f)) - pc;
  }
}

// ---------------- K2: fused bf16-MFMA GEMM + fixed-max LSE partials ----------------
// grid (32, 7, 4): x=row-block (128 rows), y=job-slot, z=column quarter (1024 cols)
// job-slot 0 = ii (computes BOTH row-LSE partials for v2f and col-LSE partials
// for f2v: the f2v ii matrix is the transpose of the v2f one, same diagonal).
// job-slots 1..6 map to original jobs 2..7 (inst-proto).
// NOTE: plain __launch_bounds__(256). (256,4) forced VGPR=64 -> scratch spills
// (WRITE_SIZE 640KB -> 234MB, 239 -> 450us). Compiler's 120 VGPR is right.
__global__ __launch_bounds__(256) void lse_mfma_kernel(
    const __bf16* __restrict__ Xa, const __bf16* __restrict__ Xf,
    const __bf16* __restrict__ Yf, const __bf16* __restrict__ Ya,
    const float* __restrict__ invdd_f, const float* __restrict__ invdd_a,
    float* __restrict__ sp, float* __restrict__ colsp,
    float* __restrict__ diagAll) {
  __shared__ __bf16 As[128 * 32];      // [row][64B] lane-linear (glds constraint)
  __shared__ __bf16 Bs[128 * 32];
  __shared__ float inv_lds[2][132];    // double-buffered: no cross-wave race
  __shared__ float part_s[2 * 128];
  __shared__ float colpart[2][128];

  const int yy = blockIdx.y;
  const int job = (yy == 0) ? 0 : yy + 1;
  const int hf = blockIdx.z;
  const int i0 = blockIdx.x * 128;

  const __bf16* Ab; const __bf16* Bb; const float* invArr = nullptr;
  if (job == 0)      { Ab = Xa; Bb = Xf; }
  else if (job <= 4) { Ab = Xa; Bb = Yf + (size_t)(job - 2) * B * D;
                       invArr = invdd_f + (job - 2) * B; }
  else               { Ab = Xf; Bb = Ya + (size_t)(job - 5) * B * D;
                       invArr = invdd_a + (job - 5) * B; }
  const bool ii = (job == 0);
  const float invT = 1.f / TEMP;
  const float inv0 = ii ? invT : invArr[0];
  const float MJ = ii ? M_II : M_IP;

  const int tid = threadIdx.x;
  const int wv = tid >> 6;
  const int lane = tid & 63;
  const int wr = (wv >> 1) * 64;
  const int wc = (wv & 1) * 64;
  const int g = lane >> 4;
  const int cl = lane & 15;

  // staging: XOR-swizzled global source so LDS fragment reads are 2-way (free)
  const int srow = lane >> 2;
  const int skoff = (((lane & 3) ^ ((lane >> 3) & 3)) * 16);
  const int c0row = wv * 16 + srow;
  const int c1row = 64 + wv * 16 + srow;
  const char* gA0 = (const char*)Ab + (size_t)(i0 + c0row) * (D * 2) + skoff;
  const char* gA1 = (const char*)Ab + (size_t)(i0 + c1row) * (D * 2) + skoff;
  __bf16* lA0 = As + wv * 512;
  __bf16* lA1 = As + 2048 + wv * 512;
  __bf16* lB0 = Bs + wv * 512;
  __bf16* lB1 = Bs + 2048 + wv * 512;

  const int csw = (g ^ ((cl >> 1) & 3)) * 8;   // swizzled k-chunk for frag reads
  int aoff[4], boff[4];
  #pragma unroll
  for (int t = 0; t < 4; ++t) {
    aoff[t] = (wr + t * 16 + cl) * 32 + csw;
    boff[t] = (wc + t * 16 + cl) * 32 + csw;
  }

  float sacc[4][4];
  #pragma unroll
  for (int ri = 0; ri < 4; ++ri)
    #pragma unroll
    for (int v = 0; v < 4; ++v) sacc[ri][v] = 0.f;

  for (int jt = hf * 8; jt < hf * 8 + 8; ++jt) {
    const int j0 = jt * 128;
    float* invL = inv_lds[jt & 1];
    if (!ii && tid < 130) {
      int idx = j0 + tid; if (idx > B - 1) idx = B - 1;
      invL[tid] = invArr[idx];
    }
    const char* gB0 = (const char*)Bb + (size_t)(j0 + c0row) * (D * 2) + skoff;
    const char* gB1 = (const char*)Bb + (size_t)(j0 + c1row) * (D * 2) + skoff;

    f32x4 acc[4][4];
    #pragma unroll
    for (int ri = 0; ri < 4; ++ri)
      #pragma unroll
      for (int ci = 0; ci < 4; ++ci) acc[ri][ci] = (f32x4){0.f, 0.f, 0.f, 0.f};

    for (int kt = 0; kt < 16; ++kt) {
      __syncthreads();
      const int kb = kt * 64;
      gload_lds16(gA0 + kb, lA0);
      gload_lds16(gA1 + kb, lA1);
      gload_lds16(gB0 + kb, lB0);
      gload_lds16(gB1 + kb, lB1);
      __syncthreads();
      bf16x8 af[4], bfr[4];
      #pragma unroll
      for (int t = 0; t < 4; ++t) {
        af[t] = *(const bf16x8*)(As + aoff[t]);
        bfr[t] = *(const bf16x8*)(Bs + boff[t]);
      }
      #pragma unroll
      for (int ri = 0; ri < 4; ++ri)
        #pragma unroll
        for (int ci = 0; ci < 4; ++ci)
          acc[ri][ci] = __builtin_amdgcn_mfma_f32_16x16x32_bf16(
              af[ri], bfr[ci], acc[ri][ci], 0, 0, 0);
    }

    // epilogue: fixed-max accumulation (rows), plus column partials for job0
    float csum[4] = {0.f, 0.f, 0.f, 0.f};
    #pragma unroll
    for (int ri = 0; ri < 4; ++ri) {
      #pragma unroll
      for (int v = 0; v < 4; ++v) {
        const int gi = i0 + wr + ri * 16 + g * 4 + v;
        float acc4 = 0.f;
        #pragma unroll
        for (int ci = 0; ci < 4; ++ci) {
          const int jloc = wc + ci * 16 + cl;
          const int gj = j0 + jloc;
          float sc;
          if (ii) sc = invT;
          else    sc = (gj == gi) ? inv0 : invL[(gj < gi) ? (jloc + 1) : jloc];
          float lv = acc[ri][ci][v] * sc;
          if (gj == gi) diagAll[(size_t)job * B + gi] = lv;
          float ev = __expf(lv - MJ);
          acc4 += ev;
          if (ii) csum[ci] += ev;
        }
        sacc[ri][v] += acc4;
      }
    }
    if (ii) {
      // column partials: reduce over the wave's 64 rows, combine row-half waves
      #pragma unroll
      for (int ci = 0; ci < 4; ++ci) {
        csum[ci] += __shfl_xor(csum[ci], 16, 64);
        csum[ci] += __shfl_xor(csum[ci], 32, 64);
      }
      if (g == 0) {
        #pragma unroll
        for (int ci = 0; ci < 4; ++ci)
          colpart[wv >> 1][wc + ci * 16 + cl] = csum[ci];
      }
      __syncthreads();
      if (tid < 128)
        colsp[(size_t)blockIdx.x * B + j0 + tid] =
            colpart[0][tid] + colpart[1][tid];
    }
  }

  // single end-of-kernel reduction: 16 lanes (columns) -> LDS -> cross-wave pair
  #pragma unroll
  for (int ri = 0; ri < 4; ++ri) {
    #pragma unroll
    for (int v = 0; v < 4; ++v) {
      float s = sacc[ri][v];
      #pragma unroll
      for (int off = 8; off >= 1; off >>= 1) s += __shfl_xor(s, off, 64);
      if (cl == 0) part_s[(wv & 1) * 128 + wr + ri * 16 + g * 4 + v] = s;
    }
  }
  __syncthreads();
  if (tid < 128) {
    size_t o = ((size_t)job * 4 + hf) * B + i0 + tid;
    sp[o] = part_s[tid] + part_s[128 + tid];
  }
}

// ---------------- K3: fused LSE-merge (blocks 0..127) + stable rank (128..159) ----------------
__global__ __launch_bounds__(256) void merge_rank_kernel(
    const float* __restrict__ sp, const float* __restrict__ colsp,
    const float* __restrict__ diagAll, const float* __restrict__ rho,
    float* __restrict__ lossAll, int* __restrict__ rankArr,
    float* __restrict__ srho) {
  __shared__ float lr[B];
  __shared__ float cnt[256];
  const int blk = blockIdx.x;
  const int t = threadIdx.x;
  if (blk < 128) {
    int idx = blk * 256 + t;          // 0 .. 8*B-1
    int job = idx >> 12;
    int i = idx & (B - 1);
    if (job == 1) {
      // f2v inst-inst: column-LSE of job0's matrix; diag equals job0's diag
      float stot = 0.f;
      #pragma unroll 4
      for (int x = 0; x < 32; ++x) stot += colsp[(size_t)x * B + i];
      lossAll[idx] = M_II + logf(stot) - diagAll[i];
    } else {
      const float* s4 = sp + (size_t)job * 4 * B + i;
      float stot = s4[0] + s4[(size_t)B] + s4[(size_t)2 * B] + s4[(size_t)3 * B];
      float MJ = (job < 2) ? M_II : M_IP;
      lossAll[idx] = MJ + logf(stot) - diagAll[(size_t)job * B + i];
    }
  } else {
    // rank: 32 blocks x 128 i's each, 2-way j-split per i
    const int base = (blk - 128) * 128;
    const int i = base + (t & 127);
    const int jlo = (t >> 7) * 2048;
    for (int k = t; k < B; k += 256) lr[k] = rho[k];
    __syncthreads();
    float my = lr[i];
    int rk = 0;
    for (int j = jlo; j < jlo + 2048; ++j) {
      float v = lr[j];
      rk += (v < my) || (v == my && j < i);   // stable: ties by index
    }
    cnt[t] = (float)rk;
    __syncthreads();
    if (t < 128) {
      int r = (int)cnt[t] + (int)cnt[t + 128];
      rankArr[i] = r;
      srho[r] = my;
    }
  }
}

// ---------------- K4: stats + gaussian pdf + cumsum + weights + final (one block) ----------------
__global__ __launch_bounds__(256) void cdf_final_kernel(
    const float* __restrict__ srho, const int* __restrict__ rankArr,
    const float* __restrict__ lossAll, float* __restrict__ out) {
  __shared__ float pdf[B];             // becomes yarr in place
  __shared__ float red[256];
  __shared__ float r1[256], r2[256];
  __shared__ float mv[2];
  const int t = threadIdx.x;
  float s = 0.f;
  for (int i = t; i < B; i += 256) s += srho[i];
  red[t] = s; __syncthreads();
  for (int off = 128; off >= 1; off >>= 1) {
    if (t < off) red[t] += red[t + off];
    __syncthreads();
  }
  float mean = red[0] / (float)B;
  __syncthreads();
  float v = 0.f;
  for (int i = t; i < B; i += 256) { float d = srho[i] - mean; v += d * d; }
  red[t] = v; __syncthreads();
  for (int off = 128; off >= 1; off >>= 1) {
    if (t < off) red[t] += red[t + off];
    __syncthreads();
  }
  if (t == 0) {
    float sd = sqrtf(red[0] / (float)B);
    mv[0] = mean + 0.3f * sd;          // mu = mean + DELTA*std
    mv[1] = sd * sqrtf(2.0f);          // sigma = std*sqrt(KA)
  }
  __syncthreads();
  float mu = mv[0], sg = mv[1];
  float c = 1.f / (2.5066282746310002f * sg);
  for (int k = t; k < B; k += 256) {
    float z = (srho[k] - mu) / sg;
    pdf[k] = expf(-0.5f * z * z) * c;
  }
  __syncthreads();
  const int base = t * (B / 256);
  float chunk = 0.f;
  for (int e = 0; e < B / 256; ++e) chunk += pdf[base + e];
  red[t] = chunk; __syncthreads();
  // Hillis-Steele inclusive scan over 256 partials (log-steps, not serial)
  #pragma unroll
  for (int off = 1; off < 256; off <<= 1) {
    float add = (t >= off) ? red[t - off] : 0.f;
    __syncthreads();
    red[t] += add;
    __syncthreads();
  }
  float run = red[t] - chunk;          // exclusive base for this chunk
  for (int e = 0; e < B / 256; ++e) { run += pdf[base + e]; pdf[base + e] = run; }
  __syncthreads();
  // ---- final: weights from rank, weighted means, scalar out ----
  const float ylast = pdf[B - 1];
  float sw = 0.f, s1 = 0.f, s2 = 0.f;
  for (int i = t; i < B; i += 256) {
    float wi = pdf[rankArr[i]] / ylast;
    float lpv = lossAll[2 * B + i] * (1.f / 27.f) + lossAll[3 * B + i] * (1.f / 9.f)
              + lossAll[4 * B + i] * (1.f / 3.f);
    float lpf = lossAll[5 * B + i] * (1.f / 27.f) + lossAll[6 * B + i] * (1.f / 9.f)
              + lossAll[7 * B + i] * (1.f / 3.f);
    sw += wi;
    s1 += wi * (lossAll[i] + lpv);
    s2 += wi * (lossAll[B + i] + lpf);
  }
  red[t] = sw; r1[t] = s1; r2[t] = s2; __syncthreads();
  for (int off = 128; off >= 1; off >>= 1) {
    if (t < off) { red[t] += red[t + off]; r1[t] += r1[t + off]; r2[t] += r2[t + off]; }
    __syncthreads();
  }
  if (t == 0) out[0] = r1[0] / red[0] + r2[0] / red[0];
}

extern "C" void kernel_launch(void* const* d_in, const int* in_sizes, int n_in,
                              void* d_out, int out_size, void* d_ws, size_t ws_size,
                              hipStream_t stream) {
  const float* audio  = (const float*)d_in[0];
  const float* frame  = (const float*)d_in[1];
  const float* a_cent = (const float*)d_in[2];
  const float* a_dens = (const float*)d_in[3];
  const float* f_cent = (const float*)d_in[4];
  const float* f_dens = (const float*)d_in[5];
  const int* vidx  = (const int*)d_in[6];
  const int* a_i2c = (const int*)d_in[7];
  const int* f_i2c = (const int*)d_in[8];
  float* out = (float*)d_out;

  const size_t BD = (size_t)B * D;
  char* base = (char*)d_ws;
  __bf16* Xa = (__bf16*)base;              base += BD * 2;
  __bf16* Xf = (__bf16*)base;              base += BD * 2;
  __bf16* Yf = (__bf16*)base;              base += 3 * BD * 2;
  __bf16* Ya = (__bf16*)base;              base += 3 * BD * 2;
  float* invdd_f = (float*)base;           base += 3 * B * 4;
  float* invdd_a = (float*)base;           base += 3 * B * 4;
  float* rho     = (float*)base;           base += B * 4;
  float* sp      = (float*)base;           base += 32 * B * 4;
  float* colsp   = (float*)base;           base += 32 * B * 4;
  float* diagAll = (float*)base;           base += 8 * B * 4;
  float* lossAll = (float*)base;           base += 8 * B * 4;
  float* srho    = (float*)base;           base += B * 4;
  int*   rankArr = (int*)base;

  prep_kernel<<<(9 * B) / 4, 256, 0, stream>>>(audio, frame, a_cent, a_dens,
                                               f_cent, f_dens, vidx, a_i2c, f_i2c,
                                               Xa, Xf, Yf, Ya, invdd_f, invdd_a, rho);

  dim3 g2(B / 128, 7, 4);
  lse_mfma_kernel<<<g2, 256, 0, stream>>>(Xa, Xf, Yf, Ya, invdd_f, invdd_a,
                                          sp, colsp, diagAll);

  merge_rank_kernel<<<160, 256, 0, stream>>>(sp, colsp, diagAll, rho,
                                             lossAll, rankArr, srho);
  cdf_final_kernel<<<1, 256, 0, stream>>>(srho, rankArr, lossAll, out);
}